// Round 5
// baseline (38.842 us; speedup 1.0000x reference)
//
#include <hip/hip_runtime.h>
#include <hip/hip_bf16.h>

#define F_IN 128
#define F_OUT 64

typedef __attribute__((ext_vector_type(8))) short short8;
typedef __attribute__((ext_vector_type(4))) float f32x4;

__device__ __forceinline__ unsigned short f2bf_rne(float f) {
  unsigned int u = __builtin_bit_cast(unsigned int, f);
  u += 0x7fffu + ((u >> 16) & 1u);
  return (unsigned short)(u >> 16);
}
__device__ __forceinline__ float bfu2f(unsigned short u) {
  return __builtin_bit_cast(float, (unsigned int)u << 16);
}
__device__ __forceinline__ float bf_lo(unsigned int u) {
  return __builtin_bit_cast(float, u << 16);
}
__device__ __forceinline__ float bf_hi(unsigned int u) {
  return __builtin_bit_cast(float, u & 0xffff0000u);
}

// ---------------------------------------------------------------------------
// Kernel A (fused): blocks [0, gemm_blocks) compute pre = bf16(x @ W) via
// MFMA; blocks [gemm_blocks, ..) compute row_ptr by binary search.
// GEMM: wave -> 16-row m-tile. W^T staged bf16 in 16 KB LDS, XOR-swizzled.
// x kept fp32-accurate via hi/lo split: acc = ah*bh + al*bh (2 MFMA).
// ---------------------------------------------------------------------------
__global__ __launch_bounds__(256) void gcn_gemm_rowptr(
    const float* __restrict__ x, const float* __restrict__ w,
    unsigned short* __restrict__ pre,
    const int* __restrict__ edge_row, int* __restrict__ row_ptr,
    int n_nodes, int n_edges, int gemm_blocks) {
  const int tid = threadIdx.x;

  if (blockIdx.x >= gemm_blocks) {  // ---- rowptr path ----
    const int r = (blockIdx.x - gemm_blocks) * 256 + tid;
    if (r > n_nodes) return;
    int lo = 0, hi = n_edges;
    while (lo < hi) {
      const int mid = (lo + hi) >> 1;
      if (edge_row[mid] < r) lo = mid + 1; else hi = mid;
    }
    row_ptr[r] = lo;
    return;
  }

  // ---- GEMM path ----
  __shared__ __align__(16) unsigned short wt_hi[64 * 128];  // 16 KB

  {  // stage W^T: coalesced float4 reads, convert, scatter u16 into LDS
#pragma unroll
    for (int i = 0; i < 8; ++i) {
      const int flat4 = tid + i * 256;
      const float4 v = ((const float4*)w)[flat4];
      const float fv[4] = {v.x, v.y, v.z, v.w};
#pragma unroll
      for (int j = 0; j < 4; ++j) {
        const int flat = flat4 * 4 + j;          // flat = k*64 + n
        const int k = flat >> 6;
        const int n = flat & 63;
        int off = (n << 8) + (k << 1);
        off ^= (n & 7) << 4;
        *(unsigned short*)((char*)wt_hi + off) = f2bf_rne(fv[j]);
      }
    }
  }
  __syncthreads();

  const int lane = tid & 63;
  const int mt = blockIdx.x * 4 + (tid >> 6);
  const int m0 = mt * 16;
  if (m0 >= n_nodes) return;

  const int lrow = lane & 15;
  const int lk = lane >> 4;
  const bool full = (m0 + 16 <= n_nodes);
  const int arow = full ? (m0 + lrow) : min(m0 + lrow, n_nodes - 1);

  f32x4 acc[4];
#pragma unroll
  for (int i = 0; i < 4; ++i) acc[i] = (f32x4){0.f, 0.f, 0.f, 0.f};

#pragma unroll
  for (int ks = 0; ks < 4; ++ks) {
    const float4* xp =
        (const float4*)(x + (size_t)arow * F_IN + ks * 32 + lk * 8);
    const float4 q0 = xp[0];
    const float4 q1 = xp[1];
    const float fv[8] = {q0.x, q0.y, q0.z, q0.w, q1.x, q1.y, q1.z, q1.w};
    short8 ah, al;
#pragma unroll
    for (int i = 0; i < 8; ++i) {
      const unsigned short h = f2bf_rne(fv[i]);
      ah[i] = (short)h;
      al[i] = (short)f2bf_rne(fv[i] - bfu2f(h));
    }
#pragma unroll
    for (int nt = 0; nt < 4; ++nt) {
      const int n = nt * 16 + lrow;
      int off = (n << 8) + (ks * 64 + lk * 16);
      off ^= (n & 7) << 4;
      const short8 bh = *(const short8*)((const char*)wt_hi + off);
      acc[nt] = __builtin_amdgcn_mfma_f32_16x16x32_bf16(ah, bh, acc[nt], 0, 0, 0);
      acc[nt] = __builtin_amdgcn_mfma_f32_16x16x32_bf16(al, bh, acc[nt], 0, 0, 0);
    }
  }

  // C/D: col = lane&15, row = (lane>>4)*4 + reg  [HW-verified]
#pragma unroll
  for (int nt = 0; nt < 4; ++nt) {
#pragma unroll
    for (int r = 0; r < 4; ++r) {
      const int row = m0 + lk * 4 + r;
      if (full || row < n_nodes)
        pre[(size_t)row * F_OUT + nt * 16 + lrow] = f2bf_rne(acc[nt][r]);
    }
  }
}

// ---------------------------------------------------------------------------
// Kernel B: out[r][f] = relu( sum_e val[e] * pre_bf16[col[e]][f] )
// One wave per row, QUARTER-WAVE per edge: quarter q (16 lanes) takes edge
// 4g+q; each lane loads uint2 = 4 bf16 features. One load instruction covers
// 4 edges; 16 edges in flight per unrolled iter. Edge metadata addresses are
// wave-uniform (row via readfirstlane) -> scalar s_load, zero LDS traffic.
// Quarter partials merged with 2 shfl_xor per feature (fixed order ->
// deterministic); quarter 0 stores a coalesced float4.
// ---------------------------------------------------------------------------
__global__ __launch_bounds__(256) void gcn_spmm(
    const unsigned short* __restrict__ pre, const int* __restrict__ row_ptr,
    const int* __restrict__ edge_col, const float* __restrict__ edge_val,
    float* __restrict__ out, int n_nodes) {
  const int lane = threadIdx.x & 63;
  const int q  = lane >> 4;   // quarter 0..3 = edge slot
  const int fl = lane & 15;   // feature quad 0..15
  int row = (int)((blockIdx.x * blockDim.x + threadIdx.x) >> 6);
  row = __builtin_amdgcn_readfirstlane(row);
  if (row >= n_nodes) return;
  const int e0 = row_ptr[row];
  const int e1 = row_ptr[row + 1];

  float a0 = 0.f, a1 = 0.f, a2 = 0.f, a3 = 0.f;
  const char* prebase = (const char*)pre + ((size_t)fl << 3);  // fl*4 u16

  int e = e0;
  for (; e + 16 <= e1; e += 16) {
#pragma unroll
    for (int g = 0; g < 4; ++g) {
      const int   cA = edge_col[e + g * 4 + 0];
      const int   cB = edge_col[e + g * 4 + 1];
      const int   cC = edge_col[e + g * 4 + 2];
      const int   cD = edge_col[e + g * 4 + 3];
      const float vA = edge_val[e + g * 4 + 0];
      const float vB = edge_val[e + g * 4 + 1];
      const float vC = edge_val[e + g * 4 + 2];
      const float vD = edge_val[e + g * 4 + 3];
      const int   cc = q < 2 ? (q == 0 ? cA : cB) : (q == 2 ? cC : cD);
      const float vv = q < 2 ? (q == 0 ? vA : vB) : (q == 2 ? vC : vD);
      const uint2 p = *(const uint2*)(prebase + ((size_t)cc << 7));
      a0 = fmaf(vv, bf_lo(p.x), a0);
      a1 = fmaf(vv, bf_hi(p.x), a1);
      a2 = fmaf(vv, bf_lo(p.y), a2);
      a3 = fmaf(vv, bf_hi(p.y), a3);
    }
  }
  for (; e < e1; e += 4) {  // tail: 4 edges/iter, zero-padded
    const int idx = e + q;
    int cc = 0;
    float vv = 0.f;
    if (idx < e1) {
      cc = edge_col[idx];
      vv = edge_val[idx];
    }
    const uint2 p = *(const uint2*)(prebase + ((size_t)cc << 7));
    a0 = fmaf(vv, bf_lo(p.x), a0);
    a1 = fmaf(vv, bf_hi(p.x), a1);
    a2 = fmaf(vv, bf_lo(p.y), a2);
    a3 = fmaf(vv, bf_hi(p.y), a3);
  }

  // cross-quarter reduce (lanes differ only in q)
  a0 += __shfl_xor(a0, 16); a0 += __shfl_xor(a0, 32);
  a1 += __shfl_xor(a1, 16); a1 += __shfl_xor(a1, 32);
  a2 += __shfl_xor(a2, 16); a2 += __shfl_xor(a2, 32);
  a3 += __shfl_xor(a3, 16); a3 += __shfl_xor(a3, 32);

  if (q == 0) {
    float4 o;
    o.x = fmaxf(a0, 0.f);
    o.y = fmaxf(a1, 0.f);
    o.z = fmaxf(a2, 0.f);
    o.w = fmaxf(a3, 0.f);
    *(float4*)(out + (size_t)row * F_OUT + fl * 4) = o;
  }
}

extern "C" void kernel_launch(void* const* d_in, const int* in_sizes, int n_in,
                              void* d_out, int out_size, void* d_ws, size_t ws_size,
                              hipStream_t stream) {
  const float* x        = (const float*)d_in[0];
  const float* w        = (const float*)d_in[1];
  const int*   edge_row = (const int*)d_in[2];
  const int*   edge_col = (const int*)d_in[3];
  const float* edge_val = (const float*)d_in[4];
  float* out = (float*)d_out;

  const int n_nodes = in_sizes[0] / F_IN;   // 50000
  const int n_edges = in_sizes[2];          // 800000

  unsigned short* pre = (unsigned short*)d_ws;  // n_nodes*64 bf16 = 6.4 MB
  int* row_ptr = (int*)((char*)d_ws +
                        (size_t)n_nodes * F_OUT * sizeof(unsigned short));

  const int m_tiles = (n_nodes + 15) / 16;
  const int gemm_blocks = (m_tiles + 3) / 4;
  const int rp_blocks = (n_nodes + 1 + 255) / 256;
  gcn_gemm_rowptr<<<gemm_blocks + rp_blocks, 256, 0, stream>>>(
      x, w, pre, edge_row, row_ptr, n_nodes, n_edges, gemm_blocks);

  const int spmm_blocks = ((size_t)n_nodes * 64 + 255) / 256;
  gcn_spmm<<<spmm_blocks, 256, 0, stream>>>(pre, row_ptr, edge_col, edge_val,
                                            out, n_nodes);
}

// Round 6
// 32.559 us; speedup vs baseline: 1.1930x; 1.1930x over previous
//
#include <hip/hip_runtime.h>
#include <hip/hip_bf16.h>

#define F_IN 128
#define F_OUT 64

typedef __attribute__((ext_vector_type(8))) short short8;
typedef __attribute__((ext_vector_type(4))) float f32x4;

__device__ __forceinline__ unsigned short f2bf_rne(float f) {
  unsigned int u = __builtin_bit_cast(unsigned int, f);
  u += 0x7fffu + ((u >> 16) & 1u);
  return (unsigned short)(u >> 16);
}
__device__ __forceinline__ float bfu2f(unsigned short u) {
  return __builtin_bit_cast(float, (unsigned int)u << 16);
}
__device__ __forceinline__ float bf_lo(unsigned int u) {
  return __builtin_bit_cast(float, u << 16);
}
__device__ __forceinline__ float bf_hi(unsigned int u) {
  return __builtin_bit_cast(float, u & 0xffff0000u);
}

// ---------------------------------------------------------------------------
// Kernel A (fused): blocks [0, gemm_blocks) compute pre = bf16(x @ W) via
// MFMA; blocks [gemm_blocks, ..) compute row_ptr by binary search.
// GEMM: wave -> 16-row m-tile. W^T staged bf16 in 16 KB LDS, XOR-swizzled.
// x kept fp32-accurate via hi/lo split: acc = ah*bh + al*bh (2 MFMA).
// ---------------------------------------------------------------------------
__global__ __launch_bounds__(256) void gcn_gemm_rowptr(
    const float* __restrict__ x, const float* __restrict__ w,
    unsigned short* __restrict__ pre,
    const int* __restrict__ edge_row, int* __restrict__ row_ptr,
    int n_nodes, int n_edges, int gemm_blocks) {
  const int tid = threadIdx.x;

  if (blockIdx.x >= gemm_blocks) {  // ---- rowptr path ----
    const int r = (blockIdx.x - gemm_blocks) * 256 + tid;
    if (r > n_nodes) return;
    int lo = 0, hi = n_edges;
    while (lo < hi) {
      const int mid = (lo + hi) >> 1;
      if (edge_row[mid] < r) lo = mid + 1; else hi = mid;
    }
    row_ptr[r] = lo;
    return;
  }

  // ---- GEMM path ----
  __shared__ __align__(16) unsigned short wt_hi[64 * 128];  // 16 KB

  {  // stage W^T: coalesced float4 reads, convert, scatter u16 into LDS
#pragma unroll
    for (int i = 0; i < 8; ++i) {
      const int flat4 = tid + i * 256;
      const float4 v = ((const float4*)w)[flat4];
      const float fv[4] = {v.x, v.y, v.z, v.w};
#pragma unroll
      for (int j = 0; j < 4; ++j) {
        const int flat = flat4 * 4 + j;          // flat = k*64 + n
        const int k = flat >> 6;
        const int n = flat & 63;
        int off = (n << 8) + (k << 1);
        off ^= (n & 7) << 4;
        *(unsigned short*)((char*)wt_hi + off) = f2bf_rne(fv[j]);
      }
    }
  }
  __syncthreads();

  const int lane = tid & 63;
  const int mt = blockIdx.x * 4 + (tid >> 6);
  const int m0 = mt * 16;
  if (m0 >= n_nodes) return;

  const int lrow = lane & 15;
  const int lk = lane >> 4;
  const bool full = (m0 + 16 <= n_nodes);
  const int arow = full ? (m0 + lrow) : min(m0 + lrow, n_nodes - 1);

  f32x4 acc[4];
#pragma unroll
  for (int i = 0; i < 4; ++i) acc[i] = (f32x4){0.f, 0.f, 0.f, 0.f};

#pragma unroll
  for (int ks = 0; ks < 4; ++ks) {
    const float4* xp =
        (const float4*)(x + (size_t)arow * F_IN + ks * 32 + lk * 8);
    const float4 q0 = xp[0];
    const float4 q1 = xp[1];
    const float fv[8] = {q0.x, q0.y, q0.z, q0.w, q1.x, q1.y, q1.z, q1.w};
    short8 ah, al;
#pragma unroll
    for (int i = 0; i < 8; ++i) {
      const unsigned short h = f2bf_rne(fv[i]);
      ah[i] = (short)h;
      al[i] = (short)f2bf_rne(fv[i] - bfu2f(h));
    }
#pragma unroll
    for (int nt = 0; nt < 4; ++nt) {
      const int n = nt * 16 + lrow;
      int off = (n << 8) + (ks * 64 + lk * 16);
      off ^= (n & 7) << 4;
      const short8 bh = *(const short8*)((const char*)wt_hi + off);
      acc[nt] = __builtin_amdgcn_mfma_f32_16x16x32_bf16(ah, bh, acc[nt], 0, 0, 0);
      acc[nt] = __builtin_amdgcn_mfma_f32_16x16x32_bf16(al, bh, acc[nt], 0, 0, 0);
    }
  }

  // C/D: col = lane&15, row = (lane>>4)*4 + reg  [HW-verified]
#pragma unroll
  for (int nt = 0; nt < 4; ++nt) {
#pragma unroll
    for (int r = 0; r < 4; ++r) {
      const int row = m0 + lk * 4 + r;
      if (full || row < n_nodes)
        pre[(size_t)row * F_OUT + nt * 16 + lrow] = f2bf_rne(acc[nt][r]);
    }
  }
}

// ---------------------------------------------------------------------------
// Kernel B: out[r][f] = relu( sum_e val[e] * pre_bf16[col[e]][f] )
// One wave per row, half-wave per edge (lanes 0-31 even edges, 32-63 odd;
// feature pair fl = lane&31 -> one uint = 2 bf16). Per 16-edge group: ALL
// 16 shuffle-pairs first, then 8 INDEPENDENT gathers issued back-to-back
// (one vmcnt wait per 16 edges), then 16 fmas on 4 accumulators. Padded
// slots have v=0 (row-0 load, L1-hit) -> no tail loop, no divergence.
// Fixed sum order -> deterministic.
// ---------------------------------------------------------------------------
__global__ __launch_bounds__(256) void gcn_spmm(
    const unsigned short* __restrict__ pre, const int* __restrict__ row_ptr,
    const int* __restrict__ edge_col, const float* __restrict__ edge_val,
    float* __restrict__ out, int n_nodes) {
  const int lane = threadIdx.x & 63;
  const int half = lane >> 5;
  const int fl = lane & 31;
  int row = (int)((blockIdx.x * blockDim.x + threadIdx.x) >> 6);
  row = __builtin_amdgcn_readfirstlane(row);
  if (row >= n_nodes) return;
  const int e0 = row_ptr[row];
  const int e1 = row_ptr[row + 1];

  float a0 = 0.f, a1 = 0.f, a2 = 0.f, a3 = 0.f;
  const char* prebase = (const char*)pre + ((size_t)fl << 2);  // fl-th uint

  for (int base = e0; base < e1; base += 64) {
    const int cnt = min(64, e1 - base);
    int myc = 0;
    float myv = 0.f;
    if (lane < cnt) {
      myc = edge_col[base + lane] << 7;  // byte offset of the row (64*2B)
      myv = edge_val[base + lane];
    }
    const int nb = (cnt + 15) >> 4;  // 16 edges per iteration
    for (int b = 0; b < nb; ++b) {
      const int j0 = b * 16;
      int   cc[8];
      float vv[8];
#pragma unroll
      for (int j = 0; j < 8; ++j) {
        const int idx = j0 + j * 2 + half;
        cc[j] = __shfl(myc, idx);
        vv[j] = __shfl(myv, idx);
      }
      unsigned int p[8];
#pragma unroll
      for (int j = 0; j < 8; ++j)
        p[j] = *(const unsigned int*)(prebase + (size_t)(unsigned int)cc[j]);
#pragma unroll
      for (int j = 0; j < 8; j += 2) {
        a0 = fmaf(vv[j], bf_lo(p[j]), a0);
        a1 = fmaf(vv[j], bf_hi(p[j]), a1);
        a2 = fmaf(vv[j + 1], bf_lo(p[j + 1]), a2);
        a3 = fmaf(vv[j + 1], bf_hi(p[j + 1]), a3);
      }
    }
  }

  // merge edge-parity halves: lanes l and l^32 hold the same feature pair
  float s0 = (a0 + a2) + __shfl_xor(a0 + a2, 32);
  float s1 = (a1 + a3) + __shfl_xor(a1 + a3, 32);
  if (half == 0) {
    float2 o = make_float2(fmaxf(s0, 0.f), fmaxf(s1, 0.f));
    *(float2*)(out + (size_t)row * F_OUT + fl * 2) = o;
  }
}

extern "C" void kernel_launch(void* const* d_in, const int* in_sizes, int n_in,
                              void* d_out, int out_size, void* d_ws, size_t ws_size,
                              hipStream_t stream) {
  const float* x        = (const float*)d_in[0];
  const float* w        = (const float*)d_in[1];
  const int*   edge_row = (const int*)d_in[2];
  const int*   edge_col = (const int*)d_in[3];
  const float* edge_val = (const float*)d_in[4];
  float* out = (float*)d_out;

  const int n_nodes = in_sizes[0] / F_IN;   // 50000
  const int n_edges = in_sizes[2];          // 800000

  unsigned short* pre = (unsigned short*)d_ws;  // n_nodes*64 bf16 = 6.4 MB
  int* row_ptr = (int*)((char*)d_ws +
                        (size_t)n_nodes * F_OUT * sizeof(unsigned short));

  const int m_tiles = (n_nodes + 15) / 16;
  const int gemm_blocks = (m_tiles + 3) / 4;
  const int rp_blocks = (n_nodes + 1 + 255) / 256;
  gcn_gemm_rowptr<<<gemm_blocks + rp_blocks, 256, 0, stream>>>(
      x, w, pre, edge_row, row_ptr, n_nodes, n_edges, gemm_blocks);

  const int spmm_blocks = ((size_t)n_nodes * 64 + 255) / 256;
  gcn_spmm<<<spmm_blocks, 256, 0, stream>>>(pre, row_ptr, edge_col, edge_val,
                                            out, n_nodes);
}